// Round 20
// baseline (576.048 us; speedup 1.0000x reference)
//
#include <hip/hip_runtime.h>
#include <hip/hip_bf16.h>

#define HH 64      // hidden
#define TT 256     // seq len
#define NB 1024    // batch
#define GG 256     // 4*H gates
#define DD0 5      // layer-0 input dim
#define DD1 128    // layer-1 input dim (2*H)

typedef __attribute__((ext_vector_type(8))) short bf16x8;   // 8 bf16 = 4 VGPR
typedef __attribute__((ext_vector_type(4))) float f32x4;    // MFMA C/D frag
typedef __attribute__((ext_vector_type(4))) unsigned int u32x4;

#define MFMA16(a, b, c) __builtin_amdgcn_mfma_f32_16x16x32_bf16((a), (b), (c), 0, 0, 0)

// lgkm-only barrier (r15): keeps global loads/stores in flight across steps.
__device__ __forceinline__ void barrier_lds() {
    asm volatile("s_waitcnt lgkmcnt(0)\n\ts_barrier" ::: "memory");
}

__device__ __forceinline__ float rcp_fast(float x) {
    float r;
    asm("v_rcp_f32 %0, %1" : "=v"(r) : "v"(x));
    return r;
}
__device__ __forceinline__ float sigf(float x) { return rcp_fast(1.0f + __expf(-x)); }
__device__ __forceinline__ float tanh_fast(float x) { return 2.0f * rcp_fast(1.0f + __expf(-2.0f * x)) - 1.0f; }

__device__ __forceinline__ float bf2f(short s) {
    unsigned int u = ((unsigned int)(unsigned short)s) << 16;
    return __builtin_bit_cast(float, u);
}
__device__ __forceinline__ short f2bf_rne(float x) {
    unsigned int u = __builtin_bit_cast(unsigned int, x);
    u += 0x7fffu + ((u >> 16) & 1u);
    return (short)(u >> 16);
}

// out0: PACKED u32[b][t][128]: low16 = h_hi bf16, high16 = h_lo bf16.

// ---------------------------------------------------------------------------
// Prep: pack x into the l0 A-fragment u32 layout, in GLOBAL memory (8.4 MB).
// xpk[(row*TT + t)*8 + s]: s 0..3 = rg0 slots, 4..7 = rg1 slots.
// ---------------------------------------------------------------------------
__global__ void prep_xpk(const float* __restrict__ x, unsigned int* __restrict__ xpk) {
    const int i = blockIdx.x * 256 + threadIdx.x;   // over NB*TT
    const float* xs = x + (size_t)i * DD0;
    unsigned int xh[5], xl[5];
#pragma unroll
    for (int d = 0; d < DD0; ++d) {
        const float v = xs[d];
        const short hi = f2bf_rne(v);
        xh[d] = (unsigned short)hi;
        xl[d] = (unsigned short)f2bf_rne(v - bf2f(hi));
    }
    unsigned int* o = xpk + (size_t)i * 8;
    o[0] = xh[0] | (xh[1] << 16);
    o[1] = xh[2] | (xh[3] << 16);
    o[2] = xh[4] | (xl[0] << 16);
    o[3] = xl[1] | (xl[2] << 16);
    o[4] = xl[3] | (xl[4] << 16);
    o[5] = xh[0] | (xh[1] << 16);
    o[6] = xh[2] | (xh[3] << 16);
    o[7] = xh[4] | (0x3f80u << 16);
}

// ---------------------------------------------------------------------------
// Layer 0, round-20: TINY-LDS co-resident recurrence. 1024 blocks = 512
// row-pairs x 2 dirs, 256 threads (4 waves). LDS = hsf2 only (1.2 KB) --
// r5/r8/r13/r16/r19 occupancy audit shows blocks co-reside only when LDS
// fits the 64 KB per-CU allocation pool; at ~1 KB we expect 3-4 blocks/CU
// with INDEPENDENT per-block barriers (fwd/bwd no longer barrier-coupled).
// x comes from the global prepacked table via a 4-deep register ring
// (lgkm-only barrier keeps the loads in flight across steps).
// A-row a = col>>3: lanes rg 0/1 duplicate row 0, rg 2/3 row 1 (benign);
// writes gated to even rg. x+bias folded in the extra MFMA k-step (r11).
// ---------------------------------------------------------------------------
__launch_bounds__(256, 1)
__global__ void lstm_l0(const unsigned int* __restrict__ xpk,
                        const float* __restrict__ w_ih_f, const float* __restrict__ w_hh_f,
                        const float* __restrict__ b_ih_f, const float* __restrict__ b_hh_f,
                        const float* __restrict__ w_ih_r, const float* __restrict__ w_hh_r,
                        const float* __restrict__ b_ih_r, const float* __restrict__ b_hh_r,
                        unsigned int* __restrict__ out0) {
    const int tid  = threadIdx.x;
    const int w    = tid >> 6;   // wave 0..3 (n-tile quad {w, w+4, w+8, w+12})
    const int l    = tid & 63;
    const int col  = l & 15;
    const int rg   = l >> 4;
    const int dir  = blockIdx.x & 1;
    const int row0 = (blockIdx.x >> 1) * 2;
    const int u    = w * 16 + col;

    const float* w_ih = dir ? w_ih_r : w_ih_f;
    const float* w_hh = dir ? w_hh_r : w_hh_f;
    const float* b_ih = dir ? b_ih_r : b_ih_f;
    const float* b_hh = dir ? b_hh_r : b_hh_f;

    __shared__ __align__(16) short hsf2[2][2 * 144];   // 1.2 KB: [buf][row*144 + k]

    for (int i = tid; i < 2 * 2 * 144; i += 256) ((short*)hsf2)[i] = 0;

    bf16x8 whh_hi[4][2], whh_lo[4][2];
#pragma unroll
    for (int q = 0; q < 4; ++q) {
        const int gate = (w + 4 * q) * 16 + col;
#pragma unroll
        for (int ks = 0; ks < 2; ++ks) {
            const float* src = w_hh + gate * HH + ks * 32 + 8 * rg;
#pragma unroll
            for (int e = 0; e < 8; ++e) {
                float v = src[e];
                short h16 = f2bf_rne(v);
                whh_hi[q][ks][e] = h16;
                whh_lo[q][ks][e] = f2bf_rne(v - bf2f(h16));
            }
        }
    }
    // x/bias B-fragment (extra k-step), r11 layout
    bf16x8 wxb[4];
#pragma unroll
    for (int q = 0; q < 4; ++q) {
        const int gate = (w + 4 * q) * 16 + col;
        short whi[5], wlo[5];
#pragma unroll
        for (int d = 0; d < DD0; ++d) {
            float v = w_ih[gate * DD0 + d];
            whi[d] = f2bf_rne(v);
            wlo[d] = f2bf_rne(v - bf2f(whi[d]));
        }
        const float bbv = b_ih[gate] + b_hh[gate];
        const short bbh = f2bf_rne(bbv);
        const short bbl = f2bf_rne(bbv - bf2f(bbh));
        bf16x8 bs = {};
        if (rg == 0) {
            bs[0] = whi[0]; bs[1] = whi[1]; bs[2] = whi[2]; bs[3] = whi[3]; bs[4] = whi[4];
            bs[5] = whi[0]; bs[6] = whi[1]; bs[7] = whi[2];
        } else if (rg == 1) {
            bs[0] = whi[3]; bs[1] = whi[4];
            bs[2] = wlo[0]; bs[3] = wlo[1]; bs[4] = wlo[2]; bs[5] = wlo[3]; bs[6] = wlo[4];
            bs[7] = bbh;
        } else if (rg == 2) {
            bs[0] = bbl;
        }
        wxb[q] = bs;
    }

    bf16x8 xf = {};
    if (rg == 2) xf[0] = (short)0x3f80;

    const int arow = col >> 3;              // A-row -> batch row (8 copies each)
    const int grow = rg >> 1;               // this lane's batch row (duplicated)
    const bool wr  = (rg & 1) == 0;         // write-gate (dedupe)

    // global x source for this lane (rg<2 only): slots rg*4..rg*4+3
    const unsigned int* xsrc = xpk + ((size_t)(row0 + arow) * TT) * 8 + rg * 4;

    // out0 running pointer
    const int t0 = dir ? (TT - 1) : 0;
    unsigned int* po = out0 + ((size_t)(row0 + grow) * TT + t0) * 128 + dir * 64 + u;
    const int pstep = dir ? -128 : 128;

    // 4-deep register prefetch ring
    u32x4 xbuf[4];
#pragma unroll
    for (int p = 0; p < 4; ++p) {
        const int ttp = dir ? (TT - 1 - p) : p;
        if (rg < 2) xbuf[p] = *(const u32x4*)&xsrc[(size_t)ttp * 8];
    }

    float cc = 0.f;
    __syncthreads();

    for (int tb = 0; tb < TT; tb += 8) {
#pragma unroll
        for (int k = 0; k < 8; ++k) {
            const int t   = tb + k;
            const int cur = t & 1, nxt = cur ^ 1;

            if (rg < 2) xf = __builtin_bit_cast(bf16x8, xbuf[k & 3]);
            // refill the slot for step t+4 (stays in flight across barriers)
            if (rg < 2 && t + 4 < TT) {
                const int ttn = dir ? (TT - 1 - (t + 4)) : (t + 4);
                xbuf[k & 3] = *(const u32x4*)&xsrc[(size_t)ttn * 8];
            }

            const short* hb = &hsf2[cur][0];
            bf16x8 ah0 = *(const bf16x8*)&hb[arow * 144 +  0 + 8 * rg];  // h_hi k 0..31
            bf16x8 ah1 = *(const bf16x8*)&hb[arow * 144 + 32 + 8 * rg];  // h_hi k 32..63
            bf16x8 ah2 = *(const bf16x8*)&hb[arow * 144 + 64 + 8 * rg];  // h_lo k 0..31
            bf16x8 ah3 = *(const bf16x8*)&hb[arow * 144 + 96 + 8 * rg];  // h_lo k 32..63
            f32x4 acc[4];
#pragma unroll
            for (int q = 0; q < 4; ++q) {
                f32x4 p0 = {0.f, 0.f, 0.f, 0.f};
                f32x4 p1 = {0.f, 0.f, 0.f, 0.f};
                p0 = MFMA16(xf, wxb[q], p0);          // x + bias k-step
                p1 = MFMA16(ah0, whh_hi[q][0], p1);
                p0 = MFMA16(ah1, whh_hi[q][1], p0);
                p1 = MFMA16(ah2, whh_hi[q][0], p1);   // h_lo * w_hi
                p0 = MFMA16(ah3, whh_hi[q][1], p0);
                p1 = MFMA16(ah0, whh_lo[q][0], p1);   // h_hi * w_lo
                p0 = MFMA16(ah1, whh_lo[q][1], p0);
                acc[q] = p0 + p1;
            }
            // C-row 4*rg -> batch row (4*rg)>>3 = rg>>1 = grow
            const float cn = sigf(acc[1][0]) * cc + sigf(acc[0][0]) * tanh_fast(acc[2][0]);
            const float hn = sigf(acc[3][0]) * tanh_fast(cn);
            cc = cn;
            const short hi16 = f2bf_rne(hn);
            const short lo16 = f2bf_rne(hn - bf2f(hi16));
            if (wr) {
                hsf2[nxt][grow * 144 + u]      = hi16;
                hsf2[nxt][grow * 144 + 64 + u] = lo16;
                *po = (unsigned int)(unsigned short)hi16 |
                      ((unsigned int)(unsigned short)lo16 << 16);
            }
            po += pstep;
            barrier_lds();
        }
    }
}

// ---------------------------------------------------------------------------
// Layer 1, PRODUCER-CONSUMER (r17/r19, unchanged): 256 blocks x 4 rows,
// wf_lo in LDS, 4-step-batched loaders, parallel gate math (1 row per lane).
// ---------------------------------------------------------------------------
__launch_bounds__(512, 1)
__global__ void lstm_l1_pc(const unsigned int* __restrict__ h0,
                           const float* __restrict__ w_ih, const float* __restrict__ w_hh,
                           const float* __restrict__ b_ih, const float* __restrict__ b_hh,
                           float* __restrict__ h_last) {
    const int tid  = threadIdx.x;
    const int W    = tid >> 6;   // wave 0..7
    const int l    = tid & 63;
    const int col  = l & 15;
    const int rg   = l >> 4;
    const int row0 = blockIdx.x * 4;

    __shared__ __align__(16) short hsf2[2][4 * 144];         // 2.3 KB
    __shared__ __align__(16) float ihaccf[2 * 4 * 64 * 20];  // 40 KB
    __shared__ __align__(16) short wflo_s[4 * 4 * 4 * 512];  // 64 KB

    for (int i = tid; i < 2 * 4 * 144; i += 512) ((short*)hsf2)[i] = 0;

    if (W < 4) {
        // ======================= LOADER =======================
        const int m = W;
        bf16x8 wf_hi[4][4];
        float bbq[4];
#pragma unroll
        for (int q = 0; q < 4; ++q) {
            const int gate = (m + 4 * q) * 16 + col;
            bbq[q] = b_ih[gate] + b_hh[gate];
#pragma unroll
            for (int ks = 0; ks < 4; ++ks) {
                const float* src = w_ih + gate * DD1 + ks * 32 + 8 * rg;
                bf16x8 hi, lo;
#pragma unroll
                for (int e = 0; e < 8; ++e) {
                    float v = src[e];
                    short h16 = f2bf_rne(v);
                    hi[e] = h16;
                    lo[e] = f2bf_rne(v - bf2f(h16));
                }
                wf_hi[q][ks] = hi;
                *(bf16x8*)&wflo_s[(((m * 4 + q) * 4 + ks) * 64 + l) * 8] = lo;
            }
        }
        const int arr = col & 3, aj = col >> 2;   // A-row a=col encodes (j, rr)
        const unsigned int* xsrc = h0 + ((size_t)(row0 + arr) * TT + aj) * 128 + 8 * rg;

        bf16x8 xA[8], xB[8];
        auto loadx = [&](int tbase, bf16x8 (&xr)[8]) {
            const unsigned int* p = xsrc + (size_t)tbase * 128;
#pragma unroll
            for (int ks = 0; ks < 4; ++ks) {
                const u32x4 a0 = *(const u32x4*)&p[ks * 32];
                const u32x4 a1 = *(const u32x4*)&p[ks * 32 + 4];
                u32x4 hw = {(a0[0] & 0xffffu) | (a0[1] << 16), (a0[2] & 0xffffu) | (a0[3] << 16),
                            (a1[0] & 0xffffu) | (a1[1] << 16), (a1[2] & 0xffffu) | (a1[3] << 16)};
                u32x4 lw = {(a0[0] >> 16) | (a0[1] & 0xffff0000u), (a0[2] >> 16) | (a0[3] & 0xffff0000u),
                            (a1[0] >> 16) | (a1[1] & 0xffff0000u), (a1[2] >> 16) | (a1[3] & 0xffff0000u)};
                xr[ks]     = __builtin_bit_cast(bf16x8, hw);
                xr[4 + ks] = __builtin_bit_cast(bf16x8, lw);
            }
        };
        auto ih_q = [&](int q, const bf16x8 (&xr)[8], int buf) {
            bf16x8 wl0 = *(const bf16x8*)&wflo_s[(((m * 4 + q) * 4 + 0) * 64 + l) * 8];
            bf16x8 wl1 = *(const bf16x8*)&wflo_s[(((m * 4 + q) * 4 + 1) * 64 + l) * 8];
            bf16x8 wl2 = *(const bf16x8*)&wflo_s[(((m * 4 + q) * 4 + 2) * 64 + l) * 8];
            bf16x8 wl3 = *(const bf16x8*)&wflo_s[(((m * 4 + q) * 4 + 3) * 64 + l) * 8];
            f32x4 a0 = {0.f, 0.f, 0.f, 0.f};
            f32x4 a1 = {0.f, 0.f, 0.f, 0.f};
            f32x4 a2 = {0.f, 0.f, 0.f, 0.f};
#pragma unroll
            for (int ks = 0; ks < 4; ++ks) a0 = MFMA16(xr[ks],     wf_hi[q][ks], a0);
#pragma unroll
            for (int ks = 0; ks < 4; ++ks) a1 = MFMA16(xr[4 + ks], wf_hi[q][ks], a1);
            a2 = MFMA16(xr[0], wl0, a2);
            a2 = MFMA16(xr[1], wl1, a2);
            a2 = MFMA16(xr[2], wl2, a2);
            a2 = MFMA16(xr[3], wl3, a2);
            f32x4 a = (a0 + a1) + a2;
            a += bbq[q];
            const int ug = m * 16 + col;
            *(f32x4*)&ihaccf[((buf * 4 + rg) * 64 + ug) * 20 + q * 4] = a;
        };

        loadx(0, xA);
        ih_q(0, xA, 0); ih_q(1, xA, 0); ih_q(2, xA, 0); ih_q(3, xA, 0);
        loadx(4, xB);
        __syncthreads();

        for (int tb = 0; tb < TT; tb += 8) {
            if (tb + 8 < TT) loadx(tb + 8, xA);
            ih_q(0, xB, 1); barrier_lds();
            ih_q(1, xB, 1); barrier_lds();
            ih_q(2, xB, 1); barrier_lds();
            ih_q(3, xB, 1); barrier_lds();
            if (tb + 12 < TT) loadx(tb + 12, xB);
            const bool doih = (tb + 8 < TT);
            if (doih) ih_q(0, xA, 0);
            barrier_lds();
            if (doih) ih_q(1, xA, 0);
            barrier_lds();
            if (doih) ih_q(2, xA, 0);
            barrier_lds();
            if (doih) ih_q(3, xA, 0);
            barrier_lds();
        }
    } else {
        // ======================= COMPUTE (parallel-gate) =======================
        const int w = W - 4;
        const int u = w * 16 + col;
        const int g = rg;
        const int arow = (l & 15) >> 2;

        bf16x8 whh_hi[4][2], whh_lo[4][2];
#pragma unroll
        for (int q = 0; q < 4; ++q) {
            const int gate = (w + 4 * q) * 16 + col;
#pragma unroll
            for (int ks = 0; ks < 2; ++ks) {
                const float* src = w_hh + gate * HH + ks * 32 + 8 * rg;
#pragma unroll
                for (int e = 0; e < 8; ++e) {
                    float v = src[e];
                    short h16 = f2bf_rne(v);
                    whh_hi[q][ks][e] = h16;
                    whh_lo[q][ks][e] = f2bf_rne(v - bf2f(h16));
                }
            }
        }

        float cc = 0.f;
        __syncthreads();

        auto step = [&](int t, int k) {
            const int cur = k & 1, nxt = cur ^ 1;
            const int j = k & 3, ib = k >> 2;
            const float* ibase = &ihaccf[((ib * 4 + j) * 64 + u) * 20 + g];
            const float iv0 = ibase[0], iv1 = ibase[4], iv2 = ibase[8], iv3 = ibase[12];
            const short* hb = &hsf2[cur][0];
            bf16x8 ah0 = *(const bf16x8*)&hb[arow * 144 +  0 + 8 * rg];
            bf16x8 ah1 = *(const bf16x8*)&hb[arow * 144 + 32 + 8 * rg];
            bf16x8 ah2 = *(const bf16x8*)&hb[arow * 144 + 64 + 8 * rg];
            bf16x8 ah3 = *(const bf16x8*)&hb[arow * 144 + 96 + 8 * rg];
            f32x4 acc[4];
#pragma unroll
            for (int q = 0; q < 4; ++q) {
                f32x4 p0 = {0.f, 0.f, 0.f, 0.f};
                f32x4 p1 = {0.f, 0.f, 0.f, 0.f};
                p0 = MFMA16(ah0, whh_hi[q][0], p0);
                p1 = MFMA16(ah1, whh_hi[q][1], p1);
                p0 = MFMA16(ah2, whh_hi[q][0], p0);
                p1 = MFMA16(ah3, whh_hi[q][1], p1);
                p0 = MFMA16(ah0, whh_lo[q][0], p0);
                p1 = MFMA16(ah1, whh_lo[q][1], p1);
                acc[q] = p0 + p1;
            }
            const float gi_ = acc[0][0] + iv0;
            const float gf_ = acc[1][0] + iv1;
            const float gg_ = acc[2][0] + iv2;
            const float go_ = acc[3][0] + iv3;
            const float cn = sigf(gf_) * cc + sigf(gi_) * tanh_fast(gg_);
            const float hn = sigf(go_) * tanh_fast(cn);
            cc = cn;
            const short hi16 = f2bf_rne(hn);
            hsf2[nxt][g * 144 + u]      = hi16;
            hsf2[nxt][g * 144 + 64 + u] = f2bf_rne(hn - bf2f(hi16));
            if (t == TT - 1) h_last[(size_t)(row0 + g) * HH + u] = hn;
            barrier_lds();
        };

        for (int tb = 0; tb < TT; tb += 8) {
#pragma unroll
            for (int k = 0; k < 8; ++k) step(tb + k, k);
        }
    }
}

// ---------------------------------------------------------------------------
// Tail: layer-1 backward is ONE step at t=T-1 from zero state, then FC.
// ---------------------------------------------------------------------------
__global__ void lstm_tail(const unsigned int* __restrict__ in0,
                          const float* __restrict__ h1f,
                          const float* __restrict__ w_ih_r,
                          const float* __restrict__ b_ih_r, const float* __restrict__ b_hh_r,
                          const float* __restrict__ fc_w, const float* __restrict__ fc_b,
                          float* __restrict__ out) {
    const int b   = blockIdx.x;
    const int tid = threadIdx.x;
    __shared__ __align__(16) float insl[DD1];
    __shared__ __align__(16) float hb[HH];
    __shared__ __align__(16) float gsh[256];

    if (tid < DD1) {
        const unsigned int v = in0[((size_t)b * TT + (TT - 1)) * 128 + tid];
        insl[tid] = bf2f((short)(v & 0xffffu)) + bf2f((short)(v >> 16));
    }
    __syncthreads();

    float a0 = b_ih_r[tid] + b_hh_r[tid], a1 = 0.f, a2 = 0.f, a3 = 0.f;
    const float4* in4 = (const float4*)insl;
#pragma unroll
    for (int kk = 0; kk < 32; ++kk) {
        float4 iv = in4[kk];
        float4 wv = *(const float4*)&w_ih_r[tid * DD1 + 4 * kk];
        a0 += wv.x * iv.x;
        a1 += wv.y * iv.y;
        a2 += wv.z * iv.z;
        a3 += wv.w * iv.w;
    }
    gsh[tid] = (a0 + a1) + (a2 + a3);
    __syncthreads();

    if (tid < HH) {
        const float gi = gsh[tid], gc = gsh[tid + 128], go = gsh[tid + 192];
        const float ccv = sigf(gi) * tanh_fast(gc);  // c_prev = 0
        hb[tid] = sigf(go) * tanh_fast(ccv);
    }
    __syncthreads();

    if (tid < 64) {
        float p = fc_w[tid] * h1f[(size_t)b * HH + tid] + fc_w[HH + tid] * hb[tid];
#pragma unroll
        for (int off = 32; off; off >>= 1) p += __shfl_xor(p, off);
        if (tid == 0) out[b] = p + fc_b[0];
    }
}

// ---------------------------------------------------------------------------
extern "C" void kernel_launch(void* const* d_in, const int* in_sizes, int n_in,
                              void* d_out, int out_size, void* d_ws, size_t ws_size,
                              hipStream_t stream) {
    const float* x = (const float*)d_in[0];
    // l0 fwd: 1..4, l0 rev: 5..8, l1 fwd: 9..12, l1 rev: 13..16, fc: 17,18
    char* ws = (char*)d_ws;
    const size_t out0_b = (size_t)NB * TT * 128 * 4;   // 134.2 MB packed u32
    const size_t h1f_b  = (size_t)NB * HH * 4;         // 256 KB

    unsigned int* out0  = (unsigned int*)ws;
    float* h1f          = (float*)(ws + out0_b);
    unsigned int* xpk   = (unsigned int*)(ws + out0_b + h1f_b);  // 8.4 MB

    prep_xpk<<<NB * TT / 256, 256, 0, stream>>>(x, xpk);
    lstm_l0<<<1024, 256, 0, stream>>>(
        xpk, (const float*)d_in[1], (const float*)d_in[2], (const float*)d_in[3], (const float*)d_in[4],
        (const float*)d_in[5], (const float*)d_in[6], (const float*)d_in[7], (const float*)d_in[8], out0);
    lstm_l1_pc<<<256, 512, 0, stream>>>(
        out0, (const float*)d_in[9], (const float*)d_in[10], (const float*)d_in[11],
        (const float*)d_in[12], h1f);
    lstm_tail<<<1024, 256, 0, stream>>>(
        out0, h1f, (const float*)d_in[13], (const float*)d_in[15], (const float*)d_in[16],
        (const float*)d_in[17], (const float*)d_in[18], (float*)d_out);
}

// Round 21
// 373.992 us; speedup vs baseline: 1.5403x; 1.5403x over previous
//
#include <hip/hip_runtime.h>
#include <hip/hip_bf16.h>

#define HH 64      // hidden
#define TT 256     // seq len
#define NB 1024    // batch
#define GG 256     // 4*H gates
#define DD0 5      // layer-0 input dim
#define DD1 128    // layer-1 input dim (2*H)

typedef __attribute__((ext_vector_type(8))) short bf16x8;   // 8 bf16 = 4 VGPR
typedef __attribute__((ext_vector_type(4))) float f32x4;    // MFMA C/D frag
typedef __attribute__((ext_vector_type(4))) unsigned int u32x4;

#define MFMA16(a, b, c) __builtin_amdgcn_mfma_f32_16x16x32_bf16((a), (b), (c), 0, 0, 0)

// lgkm-only barrier (r15): keeps global loads/stores in flight across steps.
__device__ __forceinline__ void barrier_lds() {
    asm volatile("s_waitcnt lgkmcnt(0)\n\ts_barrier" ::: "memory");
}

__device__ __forceinline__ float rcp_fast(float x) {
    float r;
    asm("v_rcp_f32 %0, %1" : "=v"(r) : "v"(x));
    return r;
}
__device__ __forceinline__ float sigf(float x) { return rcp_fast(1.0f + __expf(-x)); }
__device__ __forceinline__ float tanh_fast(float x) { return 2.0f * rcp_fast(1.0f + __expf(-2.0f * x)) - 1.0f; }

__device__ __forceinline__ float bf2f(short s) {
    unsigned int u = ((unsigned int)(unsigned short)s) << 16;
    return __builtin_bit_cast(float, u);
}
__device__ __forceinline__ short f2bf_rne(float x) {
    unsigned int u = __builtin_bit_cast(unsigned int, x);
    u += 0x7fffu + ((u >> 16) & 1u);
    return (short)(u >> 16);
}

// out0: PACKED u32[b][t][128]: low16 = h_hi bf16, high16 = h_lo bf16.

// ---------------------------------------------------------------------------
// Layer 0 (r19-proven, restored): dir-fused, parallel-gate, prepacked x
// A-fragments in LDS. 256 blocks x 512 threads; waves 0-3 fwd, 4-7 bwd.
// h per dir in hsf2[row][k] (stride 144); A-row a -> row a>>2, so C-row
// 4*rg+0 = batch row rg: every lane updates ONE row. x+bias folded in one
// extra MFMA k-step; per-step x cost = ONE ds_read_b128 from xpk.
// ---------------------------------------------------------------------------
__launch_bounds__(512, 1)
__global__ void lstm_l0(const float* __restrict__ x,
                        const float* __restrict__ w_ih_f, const float* __restrict__ w_hh_f,
                        const float* __restrict__ b_ih_f, const float* __restrict__ b_hh_f,
                        const float* __restrict__ w_ih_r, const float* __restrict__ w_hh_r,
                        const float* __restrict__ b_ih_r, const float* __restrict__ b_hh_r,
                        unsigned int* __restrict__ out0) {
    const int tid  = threadIdx.x;
    const int W    = tid >> 6;   // wave 0..7
    const int dir  = W >> 2;     // 0 = fwd, 1 = bwd
    const int w    = W & 3;      // n-tile group within dir
    const int l    = tid & 63;
    const int col  = l & 15;
    const int rg   = l >> 4;
    const int row0 = blockIdx.x * 4;
    const int u    = w * 16 + col;

    const float* w_ih = dir ? w_ih_r : w_ih_f;
    const float* w_hh = dir ? w_hh_r : w_hh_f;
    const float* b_ih = dir ? b_ih_r : b_ih_f;
    const float* b_hh = dir ? b_hh_r : b_hh_f;

    // xpk[row*2056 + t*8 + s]: prepacked x A-frag u32s (s 0..3 = rg0, 4..7 = rg1)
    __shared__ __align__(16) unsigned int xpk[4 * 2056];   // 32.9 KB
    __shared__ __align__(16) short hsf2[2][2][4 * 144];    // [dir][buf][row*144+k] 4.6 KB

    for (int i = tid; i < 4 * TT; i += 512) {
        const int row = i >> 8, t = i & 255;
        const float* xs = x + ((size_t)(row0 + row) * TT + t) * DD0;
        unsigned int xh[5], xl[5];
#pragma unroll
        for (int d = 0; d < DD0; ++d) {
            const float v = xs[d];
            const short hi = f2bf_rne(v);
            xh[d] = (unsigned short)hi;
            xl[d] = (unsigned short)f2bf_rne(v - bf2f(hi));
        }
        unsigned int* o = &xpk[row * 2056 + t * 8];
        o[0] = xh[0] | (xh[1] << 16);          // rg0: xh0 xh1
        o[1] = xh[2] | (xh[3] << 16);          //      xh2 xh3
        o[2] = xh[4] | (xl[0] << 16);          //      xh4 xl0
        o[3] = xl[1] | (xl[2] << 16);          //      xl1 xl2
        o[4] = xl[3] | (xl[4] << 16);          // rg1: xl3 xl4
        o[5] = xh[0] | (xh[1] << 16);          //      xh0 xh1
        o[6] = xh[2] | (xh[3] << 16);          //      xh2 xh3
        o[7] = xh[4] | (0x3f80u << 16);        //      xh4 1.0
    }
    for (int i = tid; i < 2 * 2 * 4 * 144; i += 512) ((short*)hsf2)[i] = 0;

    bf16x8 whh_hi[4][2], whh_lo[4][2];
#pragma unroll
    for (int q = 0; q < 4; ++q) {
        const int gate = (w + 4 * q) * 16 + col;
#pragma unroll
        for (int ks = 0; ks < 2; ++ks) {
            const float* src = w_hh + gate * HH + ks * 32 + 8 * rg;
#pragma unroll
            for (int e = 0; e < 8; ++e) {
                float v = src[e];
                short h16 = f2bf_rne(v);
                whh_hi[q][ks][e] = h16;
                whh_lo[q][ks][e] = f2bf_rne(v - bf2f(h16));
            }
        }
    }
    // x/bias B-fragment (extra k-step)
    bf16x8 wxb[4];
#pragma unroll
    for (int q = 0; q < 4; ++q) {
        const int gate = (w + 4 * q) * 16 + col;
        short whi[5], wlo[5];
#pragma unroll
        for (int d = 0; d < DD0; ++d) {
            float v = w_ih[gate * DD0 + d];
            whi[d] = f2bf_rne(v);
            wlo[d] = f2bf_rne(v - bf2f(whi[d]));
        }
        const float bbv = b_ih[gate] + b_hh[gate];
        const short bbh = f2bf_rne(bbv);
        const short bbl = f2bf_rne(bbv - bf2f(bbh));
        bf16x8 bs = {};
        if (rg == 0) {
            bs[0] = whi[0]; bs[1] = whi[1]; bs[2] = whi[2]; bs[3] = whi[3]; bs[4] = whi[4];
            bs[5] = whi[0]; bs[6] = whi[1]; bs[7] = whi[2];
        } else if (rg == 1) {
            bs[0] = whi[3]; bs[1] = whi[4];
            bs[2] = wlo[0]; bs[3] = wlo[1]; bs[4] = wlo[2]; bs[5] = wlo[3]; bs[6] = wlo[4];
            bs[7] = bbh;
        } else if (rg == 2) {
            bs[0] = bbl;
        }
        wxb[q] = bs;
    }

    bf16x8 xf = {};
    if (rg == 2) xf[0] = (short)0x3f80;

    // out0 running pointer: this lane owns (row = rg, unit u, dir)
    const int t0 = dir ? (TT - 1) : 0;
    unsigned int* po = out0 + ((size_t)(row0 + rg) * TT + t0) * 128 + dir * 64 + u;
    const int pstep = dir ? -128 : 128;

    const int arow = col >> 2;   // A-row -> batch row (4 copies each)
    float cc = 0.f;
    __syncthreads();

    for (int t = 0; t < TT; ++t) {
        const int tt  = dir ? (TT - 1 - t) : t;
        const int cur = t & 1, nxt = cur ^ 1;

        if (rg < 2)   // ONE b128 read replaces the r18 rebuild (14 VALU + 2 reads)
            xf = __builtin_bit_cast(bf16x8, *(const u32x4*)&xpk[arow * 2056 + tt * 8 + rg * 4]);

        const short* hb = &hsf2[dir][cur][0];
        bf16x8 ah0 = *(const bf16x8*)&hb[arow * 144 +  0 + 8 * rg];  // h_hi k 0..31
        bf16x8 ah1 = *(const bf16x8*)&hb[arow * 144 + 32 + 8 * rg];  // h_hi k 32..63
        bf16x8 ah2 = *(const bf16x8*)&hb[arow * 144 + 64 + 8 * rg];  // h_lo k 0..31
        bf16x8 ah3 = *(const bf16x8*)&hb[arow * 144 + 96 + 8 * rg];  // h_lo k 32..63
        f32x4 acc[4];
#pragma unroll
        for (int q = 0; q < 4; ++q) {
            f32x4 p0 = {0.f, 0.f, 0.f, 0.f};
            f32x4 p1 = {0.f, 0.f, 0.f, 0.f};
            p0 = MFMA16(xf, wxb[q], p0);          // x + bias k-step
            p1 = MFMA16(ah0, whh_hi[q][0], p1);
            p0 = MFMA16(ah1, whh_hi[q][1], p0);
            p1 = MFMA16(ah2, whh_hi[q][0], p1);   // h_lo * w_hi
            p0 = MFMA16(ah3, whh_hi[q][1], p0);
            p1 = MFMA16(ah0, whh_lo[q][0], p1);   // h_hi * w_lo
            p0 = MFMA16(ah1, whh_lo[q][1], p0);
            acc[q] = p0 + p1;
        }
        // every lane updates ONE row: C-row 4*rg+0 -> batch row rg
        const float cn = sigf(acc[1][0]) * cc + sigf(acc[0][0]) * tanh_fast(acc[2][0]);
        const float hn = sigf(acc[3][0]) * tanh_fast(cn);
        cc = cn;
        const short hi16 = f2bf_rne(hn);
        const short lo16 = f2bf_rne(hn - bf2f(hi16));
        hsf2[dir][nxt][rg * 144 + u]      = hi16;
        hsf2[dir][nxt][rg * 144 + 64 + u] = lo16;
        *po = (unsigned int)(unsigned short)hi16 |
              ((unsigned int)(unsigned short)lo16 << 16);
        po += pstep;
        barrier_lds();
    }
}

// ---------------------------------------------------------------------------
// Layer 1, PRODUCER-CONSUMER (r17/r19, unchanged): 256 blocks x 4 rows,
// wf_lo in LDS, 4-step-batched loaders, parallel gate math (1 row per lane).
// ---------------------------------------------------------------------------
__launch_bounds__(512, 1)
__global__ void lstm_l1_pc(const unsigned int* __restrict__ h0,
                           const float* __restrict__ w_ih, const float* __restrict__ w_hh,
                           const float* __restrict__ b_ih, const float* __restrict__ b_hh,
                           float* __restrict__ h_last) {
    const int tid  = threadIdx.x;
    const int W    = tid >> 6;   // wave 0..7
    const int l    = tid & 63;
    const int col  = l & 15;
    const int rg   = l >> 4;
    const int row0 = blockIdx.x * 4;

    __shared__ __align__(16) short hsf2[2][4 * 144];         // 2.3 KB
    __shared__ __align__(16) float ihaccf[2 * 4 * 64 * 20];  // 40 KB
    __shared__ __align__(16) short wflo_s[4 * 4 * 4 * 512];  // 64 KB

    for (int i = tid; i < 2 * 4 * 144; i += 512) ((short*)hsf2)[i] = 0;

    if (W < 4) {
        // ======================= LOADER =======================
        const int m = W;
        bf16x8 wf_hi[4][4];
        float bbq[4];
#pragma unroll
        for (int q = 0; q < 4; ++q) {
            const int gate = (m + 4 * q) * 16 + col;
            bbq[q] = b_ih[gate] + b_hh[gate];
#pragma unroll
            for (int ks = 0; ks < 4; ++ks) {
                const float* src = w_ih + gate * DD1 + ks * 32 + 8 * rg;
                bf16x8 hi, lo;
#pragma unroll
                for (int e = 0; e < 8; ++e) {
                    float v = src[e];
                    short h16 = f2bf_rne(v);
                    hi[e] = h16;
                    lo[e] = f2bf_rne(v - bf2f(h16));
                }
                wf_hi[q][ks] = hi;
                *(bf16x8*)&wflo_s[(((m * 4 + q) * 4 + ks) * 64 + l) * 8] = lo;
            }
        }
        const int arr = col & 3, aj = col >> 2;   // A-row a=col encodes (j, rr)
        const unsigned int* xsrc = h0 + ((size_t)(row0 + arr) * TT + aj) * 128 + 8 * rg;

        bf16x8 xA[8], xB[8];
        auto loadx = [&](int tbase, bf16x8 (&xr)[8]) {
            const unsigned int* p = xsrc + (size_t)tbase * 128;
#pragma unroll
            for (int ks = 0; ks < 4; ++ks) {
                const u32x4 a0 = *(const u32x4*)&p[ks * 32];
                const u32x4 a1 = *(const u32x4*)&p[ks * 32 + 4];
                u32x4 hw = {(a0[0] & 0xffffu) | (a0[1] << 16), (a0[2] & 0xffffu) | (a0[3] << 16),
                            (a1[0] & 0xffffu) | (a1[1] << 16), (a1[2] & 0xffffu) | (a1[3] << 16)};
                u32x4 lw = {(a0[0] >> 16) | (a0[1] & 0xffff0000u), (a0[2] >> 16) | (a0[3] & 0xffff0000u),
                            (a1[0] >> 16) | (a1[1] & 0xffff0000u), (a1[2] >> 16) | (a1[3] & 0xffff0000u)};
                xr[ks]     = __builtin_bit_cast(bf16x8, hw);
                xr[4 + ks] = __builtin_bit_cast(bf16x8, lw);
            }
        };
        auto ih_q = [&](int q, const bf16x8 (&xr)[8], int buf) {
            bf16x8 wl0 = *(const bf16x8*)&wflo_s[(((m * 4 + q) * 4 + 0) * 64 + l) * 8];
            bf16x8 wl1 = *(const bf16x8*)&wflo_s[(((m * 4 + q) * 4 + 1) * 64 + l) * 8];
            bf16x8 wl2 = *(const bf16x8*)&wflo_s[(((m * 4 + q) * 4 + 2) * 64 + l) * 8];
            bf16x8 wl3 = *(const bf16x8*)&wflo_s[(((m * 4 + q) * 4 + 3) * 64 + l) * 8];
            f32x4 a0 = {0.f, 0.f, 0.f, 0.f};
            f32x4 a1 = {0.f, 0.f, 0.f, 0.f};
            f32x4 a2 = {0.f, 0.f, 0.f, 0.f};
#pragma unroll
            for (int ks = 0; ks < 4; ++ks) a0 = MFMA16(xr[ks],     wf_hi[q][ks], a0);
#pragma unroll
            for (int ks = 0; ks < 4; ++ks) a1 = MFMA16(xr[4 + ks], wf_hi[q][ks], a1);
            a2 = MFMA16(xr[0], wl0, a2);
            a2 = MFMA16(xr[1], wl1, a2);
            a2 = MFMA16(xr[2], wl2, a2);
            a2 = MFMA16(xr[3], wl3, a2);
            f32x4 a = (a0 + a1) + a2;
            a += bbq[q];
            const int ug = m * 16 + col;
            *(f32x4*)&ihaccf[((buf * 4 + rg) * 64 + ug) * 20 + q * 4] = a;
        };

        loadx(0, xA);
        ih_q(0, xA, 0); ih_q(1, xA, 0); ih_q(2, xA, 0); ih_q(3, xA, 0);
        loadx(4, xB);
        __syncthreads();

        for (int tb = 0; tb < TT; tb += 8) {
            if (tb + 8 < TT) loadx(tb + 8, xA);
            ih_q(0, xB, 1); barrier_lds();
            ih_q(1, xB, 1); barrier_lds();
            ih_q(2, xB, 1); barrier_lds();
            ih_q(3, xB, 1); barrier_lds();
            if (tb + 12 < TT) loadx(tb + 12, xB);
            const bool doih = (tb + 8 < TT);
            if (doih) ih_q(0, xA, 0);
            barrier_lds();
            if (doih) ih_q(1, xA, 0);
            barrier_lds();
            if (doih) ih_q(2, xA, 0);
            barrier_lds();
            if (doih) ih_q(3, xA, 0);
            barrier_lds();
        }
    } else {
        // ======================= COMPUTE (parallel-gate) =======================
        const int w = W - 4;
        const int u = w * 16 + col;
        const int g = rg;
        const int arow = (l & 15) >> 2;

        bf16x8 whh_hi[4][2], whh_lo[4][2];
#pragma unroll
        for (int q = 0; q < 4; ++q) {
            const int gate = (w + 4 * q) * 16 + col;
#pragma unroll
            for (int ks = 0; ks < 2; ++ks) {
                const float* src = w_hh + gate * HH + ks * 32 + 8 * rg;
#pragma unroll
                for (int e = 0; e < 8; ++e) {
                    float v = src[e];
                    short h16 = f2bf_rne(v);
                    whh_hi[q][ks][e] = h16;
                    whh_lo[q][ks][e] = f2bf_rne(v - bf2f(h16));
                }
            }
        }

        float cc = 0.f;
        __syncthreads();

        auto step = [&](int t, int k) {
            const int cur = k & 1, nxt = cur ^ 1;
            const int j = k & 3, ib = k >> 2;
            const float* ibase = &ihaccf[((ib * 4 + j) * 64 + u) * 20 + g];
            const float iv0 = ibase[0], iv1 = ibase[4], iv2 = ibase[8], iv3 = ibase[12];
            const short* hb = &hsf2[cur][0];
            bf16x8 ah0 = *(const bf16x8*)&hb[arow * 144 +  0 + 8 * rg];
            bf16x8 ah1 = *(const bf16x8*)&hb[arow * 144 + 32 + 8 * rg];
            bf16x8 ah2 = *(const bf16x8*)&hb[arow * 144 + 64 + 8 * rg];
            bf16x8 ah3 = *(const bf16x8*)&hb[arow * 144 + 96 + 8 * rg];
            f32x4 acc[4];
#pragma unroll
            for (int q = 0; q < 4; ++q) {
                f32x4 p0 = {0.f, 0.f, 0.f, 0.f};
                f32x4 p1 = {0.f, 0.f, 0.f, 0.f};
                p0 = MFMA16(ah0, whh_hi[q][0], p0);
                p1 = MFMA16(ah1, whh_hi[q][1], p1);
                p0 = MFMA16(ah2, whh_hi[q][0], p0);
                p1 = MFMA16(ah3, whh_hi[q][1], p1);
                p0 = MFMA16(ah0, whh_lo[q][0], p0);
                p1 = MFMA16(ah1, whh_lo[q][1], p1);
                acc[q] = p0 + p1;
            }
            const float gi_ = acc[0][0] + iv0;
            const float gf_ = acc[1][0] + iv1;
            const float gg_ = acc[2][0] + iv2;
            const float go_ = acc[3][0] + iv3;
            const float cn = sigf(gf_) * cc + sigf(gi_) * tanh_fast(gg_);
            const float hn = sigf(go_) * tanh_fast(cn);
            cc = cn;
            const short hi16 = f2bf_rne(hn);
            hsf2[nxt][g * 144 + u]      = hi16;
            hsf2[nxt][g * 144 + 64 + u] = f2bf_rne(hn - bf2f(hi16));
            if (t == TT - 1) h_last[(size_t)(row0 + g) * HH + u] = hn;
            barrier_lds();
        };

        for (int tb = 0; tb < TT; tb += 8) {
#pragma unroll
            for (int k = 0; k < 8; ++k) step(tb + k, k);
        }
    }
}

// ---------------------------------------------------------------------------
// Tail: layer-1 backward is ONE step at t=T-1 from zero state, then FC.
// ---------------------------------------------------------------------------
__global__ void lstm_tail(const unsigned int* __restrict__ in0,
                          const float* __restrict__ h1f,
                          const float* __restrict__ w_ih_r,
                          const float* __restrict__ b_ih_r, const float* __restrict__ b_hh_r,
                          const float* __restrict__ fc_w, const float* __restrict__ fc_b,
                          float* __restrict__ out) {
    const int b   = blockIdx.x;
    const int tid = threadIdx.x;
    __shared__ __align__(16) float insl[DD1];
    __shared__ __align__(16) float hb[HH];
    __shared__ __align__(16) float gsh[256];

    if (tid < DD1) {
        const unsigned int v = in0[((size_t)b * TT + (TT - 1)) * 128 + tid];
        insl[tid] = bf2f((short)(v & 0xffffu)) + bf2f((short)(v >> 16));
    }
    __syncthreads();

    float a0 = b_ih_r[tid] + b_hh_r[tid], a1 = 0.f, a2 = 0.f, a3 = 0.f;
    const float4* in4 = (const float4*)insl;
#pragma unroll
    for (int kk = 0; kk < 32; ++kk) {
        float4 iv = in4[kk];
        float4 wv = *(const float4*)&w_ih_r[tid * DD1 + 4 * kk];
        a0 += wv.x * iv.x;
        a1 += wv.y * iv.y;
        a2 += wv.z * iv.z;
        a3 += wv.w * iv.w;
    }
    gsh[tid] = (a0 + a1) + (a2 + a3);
    __syncthreads();

    if (tid < HH) {
        const float gi = gsh[tid], gc = gsh[tid + 128], go = gsh[tid + 192];
        const float ccv = sigf(gi) * tanh_fast(gc);  // c_prev = 0
        hb[tid] = sigf(go) * tanh_fast(ccv);
    }
    __syncthreads();

    if (tid < 64) {
        float p = fc_w[tid] * h1f[(size_t)b * HH + tid] + fc_w[HH + tid] * hb[tid];
#pragma unroll
        for (int off = 32; off; off >>= 1) p += __shfl_xor(p, off);
        if (tid == 0) out[b] = p + fc_b[0];
    }
}

// ---------------------------------------------------------------------------
extern "C" void kernel_launch(void* const* d_in, const int* in_sizes, int n_in,
                              void* d_out, int out_size, void* d_ws, size_t ws_size,
                              hipStream_t stream) {
    const float* x = (const float*)d_in[0];
    // l0 fwd: 1..4, l0 rev: 5..8, l1 fwd: 9..12, l1 rev: 13..16, fc: 17,18
    char* ws = (char*)d_ws;
    const size_t out0_b = (size_t)NB * TT * 128 * 4;  // 134.2 MB packed u32

    unsigned int* out0 = (unsigned int*)ws;
    float* h1f = (float*)(ws + out0_b);

    lstm_l0<<<256, 512, 0, stream>>>(
        x, (const float*)d_in[1], (const float*)d_in[2], (const float*)d_in[3], (const float*)d_in[4],
        (const float*)d_in[5], (const float*)d_in[6], (const float*)d_in[7], (const float*)d_in[8], out0);
    lstm_l1_pc<<<256, 512, 0, stream>>>(
        out0, (const float*)d_in[9], (const float*)d_in[10], (const float*)d_in[11],
        (const float*)d_in[12], h1f);
    lstm_tail<<<1024, 256, 0, stream>>>(
        out0, h1f, (const float*)d_in[13], (const float*)d_in[15], (const float*)d_in[16],
        (const float*)d_in[17], (const float*)d_in[18], (float*)d_out);
}